// Round 6
// baseline (2124.094 us; speedup 1.0000x reference)
//
#include <hip/hip_runtime.h>
#include <math.h>

#define B_   8
#define CIN  1152
#define NPTS 4096
#define CH   128
#define KNN  32

// ---------------------------------------------------------------------------
// Kernel 1: 1x1 conv (W1 @ x), f64 vector FMA + BN(f64) + LeakyReLU.
// f = (float)f64 — exactly-rounded f anchors the numeric recipe.
// [round-6: f64 LDS kept (cvt at staging, exact) but CONFLICT-FREE layouts:
//  W plane-split Wp[i][k][cc] (8B lane stride -> 2-way = free), X original
//  (broadcast). Round-5's 4.7e7 conflicts came from 32B lane strides.]
// NOTE: v_mfma_f64 is broken/absent on gfx950 (round-2 evidence) — no MFMA.
// ---------------------------------------------------------------------------
__global__ __launch_bounds__(256) void k_conv_bn(
    const float* __restrict__ x, const float* __restrict__ W1,
    const float* __restrict__ gamma, const float* __restrict__ beta,
    const float* __restrict__ bmean, const float* __restrict__ bvar,
    float* __restrict__ f)
{
  __shared__ double Wp[2][4][8][33];   // [buf][plane i=c%4][k][cc=c/4]
  __shared__ double Xl[2][8][36];      // [buf][k][n] (broadcast reads)
  int bid = blockIdx.x;
  int b = bid & 7;
  int nbase = (bid >> 3) * 32;
  int t = threadIdx.x;
  int cc = t & 31, n0 = (t >> 5) * 4;      // c0 = cc*4
  int wc = t >> 1, wkp = (t & 1) * 4;      // W staging: float4 along k
  int xn = t & 31, xk = t >> 5;            // X staging: 1 float
  double acc[4][4];
#pragma unroll
  for (int i = 0; i < 4; ++i)
#pragma unroll
    for (int j = 0; j < 4; ++j) acc[i][j] = 0.0;

  // stage chunk 0 -> buf 0
  {
    float4 w4 = *(const float4*)&W1[(size_t)wc * CIN + wkp];
    Wp[0][wc & 3][wkp + 0][wc >> 2] = (double)w4.x;
    Wp[0][wc & 3][wkp + 1][wc >> 2] = (double)w4.y;
    Wp[0][wc & 3][wkp + 2][wc >> 2] = (double)w4.z;
    Wp[0][wc & 3][wkp + 3][wc >> 2] = (double)w4.w;
    Xl[0][xk][xn] = (double)x[((size_t)b * CIN + xk) * NPTS + nbase + xn];
  }
  __syncthreads();

  const int NCH = CIN / 8;   // 144 chunks
  for (int ch = 0; ch < NCH; ++ch) {
    int p = ch & 1;
    float4 wpre; float xpre;
    if (ch < NCH - 1) {
      int k0 = (ch + 1) * 8;
      wpre = *(const float4*)&W1[(size_t)wc * CIN + k0 + wkp];
      xpre = x[((size_t)b * CIN + k0 + xk) * NPTS + nbase + xn];
    }
#pragma unroll
    for (int kk = 0; kk < 8; ++kk) {
      double av0 = Wp[p][0][kk][cc];
      double av1 = Wp[p][1][kk][cc];
      double av2 = Wp[p][2][kk][cc];
      double av3 = Wp[p][3][kk][cc];
      double2 bx0 = *(const double2*)&Xl[p][kk][n0];
      double2 bx1 = *(const double2*)&Xl[p][kk][n0 + 2];
      double av[4] = {av0, av1, av2, av3};
      double bv[4] = {bx0.x, bx0.y, bx1.x, bx1.y};
#pragma unroll
      for (int i = 0; i < 4; ++i)
#pragma unroll
        for (int j = 0; j < 4; ++j) acc[i][j] = fma(av[i], bv[j], acc[i][j]);
    }
    if (ch < NCH - 1) {
      int q = p ^ 1;
      Wp[q][wc & 3][wkp + 0][wc >> 2] = (double)wpre.x;
      Wp[q][wc & 3][wkp + 1][wc >> 2] = (double)wpre.y;
      Wp[q][wc & 3][wkp + 2][wc >> 2] = (double)wpre.z;
      Wp[q][wc & 3][wkp + 3][wc >> 2] = (double)wpre.w;
      Xl[q][xk][xn] = (double)xpre;
    }
    __syncthreads();
  }

  int c0 = cc * 4;
  double rs[4], gm[4], bt[4], mu[4];
#pragma unroll
  for (int i = 0; i < 4; ++i) {
    int c = c0 + i;
    rs[i] = 1.0 / sqrt((double)bvar[c] + 1e-5);
    gm[i] = (double)gamma[c]; bt[i] = (double)beta[c]; mu[i] = (double)bmean[c];
  }
#pragma unroll
  for (int j = 0; j < 4; ++j) {
    int n = nbase + n0 + j;
    float4 o;
    float* op = &o.x;
#pragma unroll
    for (int i = 0; i < 4; ++i) {
      double v = (acc[i][j] - mu[i]) * rs[i];
      v = v * gm[i] + bt[i];
      if (v < 0.0) v = 0.2 * v;
      op[i] = (float)v;
    }
    *(float4*)&f[((size_t)b * NPTS + n) * CH + c0] = o;
  }
}

// ---------------------------------------------------------------------------
// Kernel 2: sq[row] = sum_c f[row][c]^2 — FP64-EXACT (feeds exact dist).
// ---------------------------------------------------------------------------
__global__ __launch_bounds__(256) void k_sq(const float* __restrict__ f,
                                            double* __restrict__ sq)
{
  int row = blockIdx.x * 4 + (threadIdx.x >> 6);
  int lane = threadIdx.x & 63;
  float2 v = ((const float2*)f)[(size_t)row * 64 + lane];
  double s = (double)v.x * (double)v.x + (double)v.y * (double)v.y;
#pragma unroll
  for (int sft = 1; sft < 64; sft <<= 1) s += __shfl_xor(s, sft);
  if (lane == 0) sq[row] = s;
}

// ---------------------------------------------------------------------------
// Kernel 3: M[c][c'] = sum_o Wq[o][c] * Wk[o][c'] ; grid (8,8) x 256
// ---------------------------------------------------------------------------
__global__ __launch_bounds__(256) void k_wqk(const float* __restrict__ Wq,
                                             const float* __restrict__ Wk,
                                             float* __restrict__ M)
{
  __shared__ float Ql[128][17];
  __shared__ float Kl[128][17];
  int t = threadIdx.x;
  int cb = blockIdx.x * 16;
  int db = blockIdx.y * 16;
  {
    int o = t >> 1, h = (t & 1) * 8;
    float4 a = *(const float4*)&Wq[(size_t)o * CH + cb + h];
    float4 b = *(const float4*)&Wq[(size_t)o * CH + cb + h + 4];
    Ql[o][h + 0] = a.x; Ql[o][h + 1] = a.y; Ql[o][h + 2] = a.z; Ql[o][h + 3] = a.w;
    Ql[o][h + 4] = b.x; Ql[o][h + 5] = b.y; Ql[o][h + 6] = b.z; Ql[o][h + 7] = b.w;
    float4 c4 = *(const float4*)&Wk[(size_t)o * CH + db + h];
    float4 d4 = *(const float4*)&Wk[(size_t)o * CH + db + h + 4];
    Kl[o][h + 0] = c4.x; Kl[o][h + 1] = c4.y; Kl[o][h + 2] = c4.z; Kl[o][h + 3] = c4.w;
    Kl[o][h + 4] = d4.x; Kl[o][h + 5] = d4.y; Kl[o][h + 6] = d4.z; Kl[o][h + 7] = d4.w;
  }
  __syncthreads();
  int ci = t >> 4, cj = t & 15;
  float acc = 0.f;
#pragma unroll 8
  for (int o = 0; o < 128; ++o) acc = fmaf(Ql[o][ci], Kl[o][cj], acc);
  M[(size_t)(cb + ci) * CH + db + cj] = acc;
}

// ---------------------------------------------------------------------------
// Kernel 4: qk = f @ M  ([32768 x 128] x [128 x 128]) ; grid 512 x 256
// ---------------------------------------------------------------------------
__global__ __launch_bounds__(256) void k_qk(const float* __restrict__ f,
                                            const float* __restrict__ M,
                                            float* __restrict__ qk)
{
  __shared__ float Ft[128][68];      // [k][r], 64 rows
  __shared__ float Ml[128 * 128];    // [k][c']
  int t = threadIdx.x;
  size_t rbase = (size_t)blockIdx.x * 64;
  {
    int r = t & 63, cp = (t >> 6) * 32;
    for (int i = 0; i < 8; ++i) {
      int c = cp + i * 4;
      float4 v = *(const float4*)&f[(rbase + r) * CH + c];
      Ft[c][r] = v.x; Ft[c + 1][r] = v.y; Ft[c + 2][r] = v.z; Ft[c + 3][r] = v.w;
    }
  }
  {
    const float4* Mg = (const float4*)M;
    float4* Md = (float4*)Ml;
    for (int i = 0; i < 16; ++i) Md[t + 256 * i] = Mg[t + 256 * i];
  }
  __syncthreads();
  int r0 = (t >> 4) * 4, c0 = (t & 15) * 8;
  float acc[4][8];
#pragma unroll
  for (int i = 0; i < 4; ++i)
#pragma unroll
    for (int j = 0; j < 8; ++j) acc[i][j] = 0.f;
#pragma unroll 8
  for (int k = 0; k < 128; ++k) {
    float4 a  = *(const float4*)&Ft[k][r0];
    float4 b0 = *(const float4*)&Ml[k * 128 + c0];
    float4 b1 = *(const float4*)&Ml[k * 128 + c0 + 4];
    float av[4] = {a.x, a.y, a.z, a.w};
    float bv[8] = {b0.x, b0.y, b0.z, b0.w, b1.x, b1.y, b1.z, b1.w};
#pragma unroll
    for (int i = 0; i < 4; ++i)
#pragma unroll
      for (int j = 0; j < 8; ++j) acc[i][j] = fmaf(av[i], bv[j], acc[i][j]);
  }
#pragma unroll
  for (int i = 0; i < 4; ++i) {
    float4 o0 = {acc[i][0], acc[i][1], acc[i][2], acc[i][3]};
    float4 o1 = {acc[i][4], acc[i][5], acc[i][6], acc[i][7]};
    *(float4*)&qk[(rbase + r0 + i) * CH + c0]     = o0;
    *(float4*)&qk[(rbase + r0 + i) * CH + c0 + 4] = o1;
  }
}

// ---------------------------------------------------------------------------
// Kernel 5: distance GEMM, f64 vector, 128x128 tile, 8x8 per thread,
// K chunked by 16, double-buffered f64 LDS, cvt-free CONFLICT-FREE inner:
// A original layout (broadcast reads), B plane-split Bp[j][k][mm] (8B lane
// stride, 2-way = free). D = fl32((sq_n+sq_m) - 2*sum f·f), f64 accumulate —
// bit-identical to rounds 4/5.
// ---------------------------------------------------------------------------
__global__ __launch_bounds__(256, 2) void k_dist(
    const float* __restrict__ f, const double* __restrict__ sq,
    float* __restrict__ D, int b, int rowoff)
{
  __shared__ double As[2][16][132];     // [buf][k][row]
  __shared__ double Bp[2][8][16][17];   // [buf][plane j=m%8][k][mm=m/8]
  int t = threadIdx.x;
  int nb = rowoff + blockIdx.x * 128;     // batch-local row base
  int mb = blockIdx.y * 128;              // batch-local col base
  const float* fb = f + (size_t)b * NPTS * CH;

  int lr = t & 127;          // staging row index
  int cq = (t >> 7) * 8;     // 8 channels per thread within a 16-chunk

  // stage chunk 0 -> buf 0
  {
    float4 v0 = *(const float4*)&fb[(size_t)(nb + lr) * CH + cq];
    float4 v1 = *(const float4*)&fb[(size_t)(nb + lr) * CH + cq + 4];
    As[0][cq + 0][lr] = (double)v0.x; As[0][cq + 1][lr] = (double)v0.y;
    As[0][cq + 2][lr] = (double)v0.z; As[0][cq + 3][lr] = (double)v0.w;
    As[0][cq + 4][lr] = (double)v1.x; As[0][cq + 5][lr] = (double)v1.y;
    As[0][cq + 6][lr] = (double)v1.z; As[0][cq + 7][lr] = (double)v1.w;
    float4 u0 = *(const float4*)&fb[(size_t)(mb + lr) * CH + cq];
    float4 u1 = *(const float4*)&fb[(size_t)(mb + lr) * CH + cq + 4];
    int pl = lr & 7, mm = lr >> 3;
    Bp[0][pl][cq + 0][mm] = (double)u0.x; Bp[0][pl][cq + 1][mm] = (double)u0.y;
    Bp[0][pl][cq + 2][mm] = (double)u0.z; Bp[0][pl][cq + 3][mm] = (double)u0.w;
    Bp[0][pl][cq + 4][mm] = (double)u1.x; Bp[0][pl][cq + 5][mm] = (double)u1.y;
    Bp[0][pl][cq + 6][mm] = (double)u1.z; Bp[0][pl][cq + 7][mm] = (double)u1.w;
  }
  __syncthreads();

  int r0 = (t >> 4) * 8, mm = t & 15, m0 = mm * 8;
  double acc[8][8];
#pragma unroll
  for (int i = 0; i < 8; ++i)
#pragma unroll
    for (int j = 0; j < 8; ++j) acc[i][j] = 0.0;

#pragma unroll
  for (int ch = 0; ch < 8; ++ch) {
    int p = ch & 1;
    float4 pa0, pa1, pb0, pb1;
    if (ch < 7) {
      int cb2 = (ch + 1) * 16 + cq;
      pa0 = *(const float4*)&fb[(size_t)(nb + lr) * CH + cb2];
      pa1 = *(const float4*)&fb[(size_t)(nb + lr) * CH + cb2 + 4];
      pb0 = *(const float4*)&fb[(size_t)(mb + lr) * CH + cb2];
      pb1 = *(const float4*)&fb[(size_t)(mb + lr) * CH + cb2 + 4];
    }
#pragma unroll 4
    for (int kk = 0; kk < 16; ++kk) {
      double2 a0 = *(const double2*)&As[p][kk][r0];
      double2 a1 = *(const double2*)&As[p][kk][r0 + 2];
      double2 a2 = *(const double2*)&As[p][kk][r0 + 4];
      double2 a3 = *(const double2*)&As[p][kk][r0 + 6];
      double bv[8];
#pragma unroll
      for (int j = 0; j < 8; ++j) bv[j] = Bp[p][j][kk][mm];
      double av[8] = {a0.x, a0.y, a1.x, a1.y, a2.x, a2.y, a3.x, a3.y};
#pragma unroll
      for (int i = 0; i < 8; ++i)
#pragma unroll
        for (int j = 0; j < 8; ++j) acc[i][j] = fma(av[i], bv[j], acc[i][j]);
    }
    if (ch < 7) {
      int q = p ^ 1;
      As[q][cq + 0][lr] = (double)pa0.x; As[q][cq + 1][lr] = (double)pa0.y;
      As[q][cq + 2][lr] = (double)pa0.z; As[q][cq + 3][lr] = (double)pa0.w;
      As[q][cq + 4][lr] = (double)pa1.x; As[q][cq + 5][lr] = (double)pa1.y;
      As[q][cq + 6][lr] = (double)pa1.z; As[q][cq + 7][lr] = (double)pa1.w;
      int pl = lr & 7, mw = lr >> 3;
      Bp[q][pl][cq + 0][mw] = (double)pb0.x; Bp[q][pl][cq + 1][mw] = (double)pb0.y;
      Bp[q][pl][cq + 2][mw] = (double)pb0.z; Bp[q][pl][cq + 3][mw] = (double)pb0.w;
      Bp[q][pl][cq + 4][mw] = (double)pb1.x; Bp[q][pl][cq + 5][mw] = (double)pb1.y;
      Bp[q][pl][cq + 6][mw] = (double)pb1.z; Bp[q][pl][cq + 7][mw] = (double)pb1.w;
    }
    __syncthreads();
  }

  double sqn[8], sqm[8];
#pragma unroll
  for (int i = 0; i < 8; ++i) sqn[i] = sq[(size_t)b * NPTS + nb + r0 + i];
#pragma unroll
  for (int j = 0; j < 8; ++j) sqm[j] = sq[(size_t)b * NPTS + mb + m0 + j];
#pragma unroll
  for (int i = 0; i < 8; ++i) {
    int rloc = blockIdx.x * 128 + r0 + i;   // chunk-local row
    float4 o;
    o.x = (float)((sqn[i] + sqm[0]) - 2.0 * acc[i][0]);
    o.y = (float)((sqn[i] + sqm[1]) - 2.0 * acc[i][1]);
    o.z = (float)((sqn[i] + sqm[2]) - 2.0 * acc[i][2]);
    o.w = (float)((sqn[i] + sqm[3]) - 2.0 * acc[i][3]);
    *(float4*)&D[(size_t)rloc * NPTS + mb + m0] = o;
    o.x = (float)((sqn[i] + sqm[4]) - 2.0 * acc[i][4]);
    o.y = (float)((sqn[i] + sqm[5]) - 2.0 * acc[i][5]);
    o.z = (float)((sqn[i] + sqm[6]) - 2.0 * acc[i][6]);
    o.w = (float)((sqn[i] + sqm[7]) - 2.0 * acc[i][7]);
    *(float4*)&D[(size_t)rloc * NPTS + mb + m0 + 4] = o;
  }
}

// ---------------------------------------------------------------------------
// Kernel 6: radix-select exact top-32. Set = {keys < thr_key} ∪ lowest-index
// {keys == thr_key} — identical to stable top_k's set given identical keys.
// + attention + std-over-K. grid = chunk, block 256.
// ---------------------------------------------------------------------------
__device__ __forceinline__ unsigned int sortkey(float x) {
  unsigned int u = __float_as_uint(x);
  return (u & 0x80000000u) ? ~u : (u | 0x80000000u);
}

__global__ __launch_bounds__(256) void k_select(
    const float* __restrict__ D, const float* __restrict__ f,
    const float* __restrict__ qk, float* __restrict__ sv,
    int b, int rowoff)
{
  __shared__ unsigned int keys[NPTS];      // 16 KB sortable keys
  __shared__ unsigned int hist[4][257];    // wave-private, bank-staggered
  __shared__ unsigned int wsum[4];
  __shared__ unsigned int eqw[4];
  __shared__ unsigned int sh_bucket, sh_excl, nkept;
  __shared__ int   kept[KNN];
  __shared__ float qkl[CH];
  __shared__ float fc[CH];
  __shared__ float eng[KNN];

  int t = threadIdx.x;
  int row = rowoff + blockIdx.x;            // batch-local row
  const float* fb = f + (size_t)b * NPTS * CH;

  {
    const float4* Dp = (const float4*)(D + (size_t)blockIdx.x * NPTS);
#pragma unroll
    for (int i = 0; i < 4; ++i) {
      float4 v = Dp[t + 256 * i];
      uint4 u;
      u.x = sortkey(v.x); u.y = sortkey(v.y);
      u.z = sortkey(v.z); u.w = sortkey(v.w);
      ((uint4*)keys)[t + 256 * i] = u;
    }
  }
  if (t == 0) nkept = 0;
  if (t < 32) {
    ((float4*)qkl)[t] = ((const float4*)(qk + ((size_t)b * NPTS + row) * CH))[t];
  } else if (t < 64) {
    ((float4*)fc)[t - 32] = ((const float4*)(fb + (size_t)row * CH))[t - 32];
  }
  __syncthreads();

  // 4-pass 8-bit radix select: find exact key of rank KNN (1-based)
  unsigned int prefix = 0;
  unsigned int target = KNN;
  unsigned int cnt_less = 0;
  int wv = t >> 6;
  for (int pass = 0; pass < 4; ++pass) {
    int shift = 24 - pass * 8;
    hist[0][t] = 0; hist[1][t] = 0; hist[2][t] = 0; hist[3][t] = 0;
    __syncthreads();
#pragma unroll
    for (int i = 0; i < 16; ++i) {
      unsigned int k = keys[t + 256 * i];
      bool m = (pass == 0) || ((k >> (shift + 8)) == prefix);
      if (m) atomicAdd(&hist[wv][(k >> shift) & 255u], 1u);
    }
    __syncthreads();
    unsigned int v = hist[0][t] + hist[1][t] + hist[2][t] + hist[3][t];
    unsigned int sc = v;
#pragma unroll
    for (int d = 1; d < 64; d <<= 1) {
      unsigned int nn = __shfl_up(sc, d);
      if ((t & 63) >= d) sc += nn;
    }
    if ((t & 63) == 63) wsum[t >> 6] = sc;
    __syncthreads();
    unsigned int wo = 0;
#pragma unroll
    for (int w = 0; w < 4; ++w) wo += (w < (t >> 6)) ? wsum[w] : 0u;
    unsigned int incl = sc + wo;
    unsigned int excl = incl - v;
    if (excl < target && target <= incl) { sh_bucket = (unsigned int)t; sh_excl = excl; }
    __syncthreads();
    prefix = (prefix << 8) | sh_bucket;
    target -= sh_excl;
    cnt_less += sh_excl;
    __syncthreads();
  }
  unsigned int thr_key = prefix;

  // compact strictly-less (arbitrary slot order; set semantics)
#pragma unroll
  for (int i = 0; i < 16; ++i) {
    int idx = t + 256 * i;
    if (keys[idx] < thr_key) {
      unsigned int p = atomicAdd(&nkept, 1u);
      kept[p] = idx;
    }
  }
  // fill remaining slots with ==thr_key elements in increasing index order
  {
    unsigned int eqloc = 0;
#pragma unroll
    for (int j = 0; j < 16; ++j)
      eqloc += (keys[t * 16 + ((j + t) & 15)] == thr_key) ? 1u : 0u;
    unsigned int esc = eqloc;
#pragma unroll
    for (int d = 1; d < 64; d <<= 1) {
      unsigned int nn = __shfl_up(esc, d);
      if ((t & 63) >= d) esc += nn;
    }
    if ((t & 63) == 63) eqw[t >> 6] = esc;
    __syncthreads();
    unsigned int ewo = 0;
#pragma unroll
    for (int w = 0; w < 4; ++w) ewo += (w < (t >> 6)) ? eqw[w] : 0u;
    unsigned int slot = cnt_less + (esc + ewo - eqloc);
#pragma unroll
    for (int j = 0; j < 16; ++j) {
      if (keys[t * 16 + j] == thr_key) {
        if (slot < KNN) kept[slot] = t * 16 + j;
        slot++;
      }
    }
  }
  __syncthreads();

  // energies: e_k = qk_n . (f_m - f_n) / sqrt(128)
  {
    int kk = t >> 3, lg = t & 7;
    int mg = kept[kk];
    const float* fm = fb + (size_t)mg * CH;
    float dd = 0.f, ds = 0.f;
#pragma unroll
    for (int i = 0; i < 4; ++i) {
      float4 qv = *(const float4*)&qkl[lg * 16 + i * 4];
      float4 vm = *(const float4*)&fm[lg * 16 + i * 4];
      float4 vc = *(const float4*)&fc[lg * 16 + i * 4];
      dd = fmaf(qv.x, vm.x, dd); dd = fmaf(qv.y, vm.y, dd);
      dd = fmaf(qv.z, vm.z, dd); dd = fmaf(qv.w, vm.w, dd);
      ds = fmaf(qv.x, vc.x, ds); ds = fmaf(qv.y, vc.y, ds);
      ds = fmaf(qv.z, vc.z, ds); ds = fmaf(qv.w, vc.w, ds);
    }
#pragma unroll
    for (int m = 1; m < 8; m <<= 1) { dd += __shfl_xor(dd, m); ds += __shfl_xor(ds, m); }
    if (lg == 0) eng[kk] = (dd - ds) * 0.08838834764831845f;
  }
  __syncthreads();

  // softmax over K + biased std over K (lanes 0..31 of wave 0)
  if (t < 64) {
    float e = (t < 32) ? eng[t] : -INFINITY;
    float mx = e;
#pragma unroll
    for (int m = 1; m < 32; m <<= 1) mx = fmaxf(mx, __shfl_xor(mx, m));
    float ex = (t < 32) ? expf(e - mx) : 0.f;
    float sm = ex;
#pragma unroll
    for (int m = 1; m < 32; m <<= 1) sm += __shfl_xor(sm, m);
    float a  = (t < 32) ? (ex / sm) : 0.f;
    float sa = a;
#pragma unroll
    for (int m = 1; m < 32; m <<= 1) sa += __shfl_xor(sa, m);
    float mean = sa * (1.f / 32.f);
    float dv = (t < 32) ? (a - mean) : 0.f;
    float vr = dv * dv;
#pragma unroll
    for (int m = 1; m < 32; m <<= 1) vr += __shfl_xor(vr, m);
    if (t == 0) sv[(size_t)b * NPTS + row] = sqrtf(vr * (1.f / 32.f));
  }
}

// ---------------------------------------------------------------------------
// Kernel 7: per-cloud standardize (ddof=1) + modified sigmoid; grid 8 x 256
// ---------------------------------------------------------------------------
__global__ __launch_bounds__(256) void k_final(const float* __restrict__ s,
                                               float* __restrict__ out)
{
  __shared__ float red[4];
  int b = blockIdx.x, t = threadIdx.x;
  const float4* sp = (const float4*)(s + (size_t)b * NPTS);
  float4* op = (float4*)(out + (size_t)b * NPTS);
  float4 vs[4];
  float loc = 0.f;
#pragma unroll
  for (int i = 0; i < 4; ++i) {
    vs[i] = sp[t + 256 * i];
    loc += vs[i].x + vs[i].y + vs[i].z + vs[i].w;
  }
#pragma unroll
  for (int sft = 1; sft < 64; sft <<= 1) loc += __shfl_xor(loc, sft);
  if ((t & 63) == 0) red[t >> 6] = loc;
  __syncthreads();
  float meanv = (red[0] + red[1] + red[2] + red[3]) * (1.f / 4096.f);
  __syncthreads();
  float loc2 = 0.f;
#pragma unroll
  for (int i = 0; i < 4; ++i) {
    float dx = vs[i].x - meanv, dy = vs[i].y - meanv;
    float dz = vs[i].z - meanv, dw = vs[i].w - meanv;
    loc2 += dx * dx + dy * dy + dz * dz + dw * dw;
  }
#pragma unroll
  for (int sft = 1; sft < 64; sft <<= 1) loc2 += __shfl_xor(loc2, sft);
  if ((t & 63) == 0) red[t >> 6] = loc2;
  __syncthreads();
  float var = (red[0] + red[1] + red[2] + red[3]) * (1.f / 4095.f);
  float rstd = rsqrtf(var);
  const float L20 = 4.3219280948873623f;  // log2(20)
#pragma unroll
  for (int i = 0; i < 4; ++i) {
    float4 v = vs[i], o;
    o.x = 1.f / (1.f + exp2f(-(v.x - meanv) * rstd * L20));
    o.y = 1.f / (1.f + exp2f(-(v.y - meanv) * rstd * L20));
    o.z = 1.f / (1.f + exp2f(-(v.z - meanv) * rstd * L20));
    o.w = 1.f / (1.f + exp2f(-(v.w - meanv) * rstd * L20));
    op[t + 256 * i] = o;
  }
}

// ---------------------------------------------------------------------------
extern "C" void kernel_launch(void* const* d_in, const int* in_sizes, int n_in,
                              void* d_out, int out_size, void* d_ws, size_t ws_size,
                              hipStream_t stream)
{
  const float* x     = (const float*)d_in[0];
  const float* W1    = (const float*)d_in[1];
  const float* gamma = (const float*)d_in[2];
  const float* beta  = (const float*)d_in[3];
  const float* bmean = (const float*)d_in[4];
  const float* bvar  = (const float*)d_in[5];
  const float* Wq    = (const float*)d_in[6];
  const float* Wk    = (const float*)d_in[7];
  float* out = (float*)d_out;

  float*  f   = (float*)d_ws;                               // 16 MB
  float*  qk  = f  + (size_t)B_ * NPTS * CH;                // 16 MB
  double* sqd = (double*)(qk + (size_t)B_ * NPTS * CH);     // 256 KB (f64)
  float*  sv  = (float*)(sqd + (size_t)B_ * NPTS);          // 128 KB
  float*  M   = sv + (size_t)B_ * NPTS;                     // 64 KB
  float*  D   = M  + (size_t)CH * CH;                       // chunk*4096*4 B

  // pick the largest chunk that fits the workspace (deterministic: ws_size
  // is constant across calls). 4096 -> 64 MB D; 2048 -> 32 MB; 1024 -> 16 MB.
  size_t fixed_bytes = (size_t)((char*)D - (char*)d_ws);
  size_t avail = (ws_size > fixed_bytes) ? (ws_size - fixed_bytes) : 0;
  int chunk = 1024;
  if (avail >= (size_t)4096 * NPTS * 4) chunk = 4096;
  else if (avail >= (size_t)2048 * NPTS * 4) chunk = 2048;

  hipLaunchKernelGGL(k_conv_bn, dim3(1024), dim3(256), 0, stream,
                     x, W1, gamma, beta, bmean, bvar, f);
  hipLaunchKernelGGL(k_sq, dim3(8192), dim3(256), 0, stream, f, sqd);
  hipLaunchKernelGGL(k_wqk, dim3(8, 8), dim3(256), 0, stream, Wq, Wk, M);
  hipLaunchKernelGGL(k_qk, dim3(512), dim3(256), 0, stream, f, M, qk);
  for (int b = 0; b < B_; ++b) {
    for (int ro = 0; ro < NPTS; ro += chunk) {
      hipLaunchKernelGGL(k_dist, dim3(chunk / 128, 32), dim3(256), 0, stream,
                         f, sqd, D, b, ro);
      hipLaunchKernelGGL(k_select, dim3(chunk), dim3(256), 0, stream,
                         D, f, qk, sv, b, ro);
    }
  }
  hipLaunchKernelGGL(k_final, dim3(8), dim3(256), 0, stream, sv, out);
}

// Round 7
// 1920.377 us; speedup vs baseline: 1.1061x; 1.1061x over previous
//
#include <hip/hip_runtime.h>
#include <math.h>

#define B_   8
#define CIN  1152
#define NPTS 4096
#define CH   128
#define KNN  32

// ---------------------------------------------------------------------------
// Kernel 1: 1x1 conv (W1 @ x) in FP64 vector + BN(inference, f64) + LeakyReLU
// f = (float)f64. [round-4 verbatim — best measured conv: 310 µs, VALUBusy 66.
// f64-LDS variants (r5/r6) were slower: LDS-pipe-bound. cvt tax stays.]
// NOTE: v_mfma_f64 is broken/absent on gfx950 (round-2 evidence) — no MFMA.
// ---------------------------------------------------------------------------
__global__ __launch_bounds__(256) void k_conv_bn(
    const float* __restrict__ x, const float* __restrict__ W1,
    const float* __restrict__ gamma, const float* __restrict__ beta,
    const float* __restrict__ bmean, const float* __restrict__ bvar,
    float* __restrict__ f)
{
  __shared__ float Wl[8][132];   // [k][c]
  __shared__ float Xl[8][36];    // [k][n]
  int bid = blockIdx.x;
  int b = bid & 7;
  int nbase = (bid >> 3) * 32;
  int t = threadIdx.x;
  int c0 = (t & 31) * 4, n0 = (t >> 5) * 4;
  double acc[4][4];
#pragma unroll
  for (int i = 0; i < 4; ++i)
#pragma unroll
    for (int j = 0; j < 4; ++j) acc[i][j] = 0.0;

  for (int k0 = 0; k0 < CIN; k0 += 8) {
    {
      int c = t >> 1, kp = (t & 1) * 4;
      float4 w4 = *(const float4*)&W1[(size_t)c * CIN + k0 + kp];
      Wl[kp + 0][c] = w4.x; Wl[kp + 1][c] = w4.y;
      Wl[kp + 2][c] = w4.z; Wl[kp + 3][c] = w4.w;
    }
    {
      int k = t >> 5, n = t & 31;
      Xl[k][n] = x[((size_t)b * CIN + (k0 + k)) * NPTS + nbase + n];
    }
    __syncthreads();
#pragma unroll
    for (int kk = 0; kk < 8; ++kk) {
      float4 a  = *(const float4*)&Wl[kk][c0];
      float4 b0 = *(const float4*)&Xl[kk][n0];
      double av[4] = {(double)a.x, (double)a.y, (double)a.z, (double)a.w};
      double bv[4] = {(double)b0.x, (double)b0.y, (double)b0.z, (double)b0.w};
#pragma unroll
      for (int i = 0; i < 4; ++i)
#pragma unroll
        for (int j = 0; j < 4; ++j) acc[i][j] = fma(av[i], bv[j], acc[i][j]);
    }
    __syncthreads();
  }
  double rs[4], gm[4], bt[4], mu[4];
#pragma unroll
  for (int i = 0; i < 4; ++i) {
    int c = c0 + i;
    rs[i] = 1.0 / sqrt((double)bvar[c] + 1e-5);
    gm[i] = (double)gamma[c]; bt[i] = (double)beta[c]; mu[i] = (double)bmean[c];
  }
#pragma unroll
  for (int j = 0; j < 4; ++j) {
    int n = nbase + n0 + j;
    float4 o;
    float* op = &o.x;
#pragma unroll
    for (int i = 0; i < 4; ++i) {
      double v = (acc[i][j] - mu[i]) * rs[i];
      v = v * gm[i] + bt[i];
      if (v < 0.0) v = 0.2 * v;
      op[i] = (float)v;
    }
    *(float4*)&f[((size_t)b * NPTS + n) * CH + c0] = o;
  }
}

// ---------------------------------------------------------------------------
// Kernel 2: sq[row] = sum_c f[row][c]^2 — FP64-EXACT (feeds exact dist).
// ---------------------------------------------------------------------------
__global__ __launch_bounds__(256) void k_sq(const float* __restrict__ f,
                                            double* __restrict__ sq)
{
  int row = blockIdx.x * 4 + (threadIdx.x >> 6);
  int lane = threadIdx.x & 63;
  float2 v = ((const float2*)f)[(size_t)row * 64 + lane];
  double s = (double)v.x * (double)v.x + (double)v.y * (double)v.y;
#pragma unroll
  for (int sft = 1; sft < 64; sft <<= 1) s += __shfl_xor(s, sft);
  if (lane == 0) sq[row] = s;
}

// ---------------------------------------------------------------------------
// Kernel 3: M[c][c'] = sum_o Wq[o][c] * Wk[o][c'] ; grid (8,8) x 256
// ---------------------------------------------------------------------------
__global__ __launch_bounds__(256) void k_wqk(const float* __restrict__ Wq,
                                             const float* __restrict__ Wk,
                                             float* __restrict__ M)
{
  __shared__ float Ql[128][17];
  __shared__ float Kl[128][17];
  int t = threadIdx.x;
  int cb = blockIdx.x * 16;
  int db = blockIdx.y * 16;
  {
    int o = t >> 1, h = (t & 1) * 8;
    float4 a = *(const float4*)&Wq[(size_t)o * CH + cb + h];
    float4 b = *(const float4*)&Wq[(size_t)o * CH + cb + h + 4];
    Ql[o][h + 0] = a.x; Ql[o][h + 1] = a.y; Ql[o][h + 2] = a.z; Ql[o][h + 3] = a.w;
    Ql[o][h + 4] = b.x; Ql[o][h + 5] = b.y; Ql[o][h + 6] = b.z; Ql[o][h + 7] = b.w;
    float4 c4 = *(const float4*)&Wk[(size_t)o * CH + db + h];
    float4 d4 = *(const float4*)&Wk[(size_t)o * CH + db + h + 4];
    Kl[o][h + 0] = c4.x; Kl[o][h + 1] = c4.y; Kl[o][h + 2] = c4.z; Kl[o][h + 3] = c4.w;
    Kl[o][h + 4] = d4.x; Kl[o][h + 5] = d4.y; Kl[o][h + 6] = d4.z; Kl[o][h + 7] = d4.w;
  }
  __syncthreads();
  int ci = t >> 4, cj = t & 15;
  float acc = 0.f;
#pragma unroll 8
  for (int o = 0; o < 128; ++o) acc = fmaf(Ql[o][ci], Kl[o][cj], acc);
  M[(size_t)(cb + ci) * CH + db + cj] = acc;
}

// ---------------------------------------------------------------------------
// Kernel 4: qk = f @ M  ([32768 x 128] x [128 x 128]) ; grid 512 x 256
// ---------------------------------------------------------------------------
__global__ __launch_bounds__(256) void k_qk(const float* __restrict__ f,
                                            const float* __restrict__ M,
                                            float* __restrict__ qk)
{
  __shared__ float Ft[128][68];      // [k][r], 64 rows
  __shared__ float Ml[128 * 128];    // [k][c']
  int t = threadIdx.x;
  size_t rbase = (size_t)blockIdx.x * 64;
  {
    int r = t & 63, cp = (t >> 6) * 32;
    for (int i = 0; i < 8; ++i) {
      int c = cp + i * 4;
      float4 v = *(const float4*)&f[(rbase + r) * CH + c];
      Ft[c][r] = v.x; Ft[c + 1][r] = v.y; Ft[c + 2][r] = v.z; Ft[c + 3][r] = v.w;
    }
  }
  {
    const float4* Mg = (const float4*)M;
    float4* Md = (float4*)Ml;
    for (int i = 0; i < 16; ++i) Md[t + 256 * i] = Mg[t + 256 * i];
  }
  __syncthreads();
  int r0 = (t >> 4) * 4, c0 = (t & 15) * 8;
  float acc[4][8];
#pragma unroll
  for (int i = 0; i < 4; ++i)
#pragma unroll
    for (int j = 0; j < 8; ++j) acc[i][j] = 0.f;
#pragma unroll 8
  for (int k = 0; k < 128; ++k) {
    float4 a  = *(const float4*)&Ft[k][r0];
    float4 b0 = *(const float4*)&Ml[k * 128 + c0];
    float4 b1 = *(const float4*)&Ml[k * 128 + c0 + 4];
    float av[4] = {a.x, a.y, a.z, a.w};
    float bv[8] = {b0.x, b0.y, b0.z, b0.w, b1.x, b1.y, b1.z, b1.w};
#pragma unroll
    for (int i = 0; i < 4; ++i)
#pragma unroll
      for (int j = 0; j < 8; ++j) acc[i][j] = fmaf(av[i], bv[j], acc[i][j]);
  }
#pragma unroll
  for (int i = 0; i < 4; ++i) {
    float4 o0 = {acc[i][0], acc[i][1], acc[i][2], acc[i][3]};
    float4 o1 = {acc[i][4], acc[i][5], acc[i][6], acc[i][7]};
    *(float4*)&qk[(rbase + r0 + i) * CH + c0]     = o0;
    *(float4*)&qk[(rbase + r0 + i) * CH + c0 + 4] = o1;
  }
}

// ---------------------------------------------------------------------------
// Kernel 5: distance GEMM [round-4 verbatim — best measured]. f64 vector,
// 128x128 tile, 8x8/thread, K chunked by 32, double-buffered f32 LDS,
// register prefetch. D = fl32((sq_n+sq_m) - 2*sum f·f), exact in f64.
// ---------------------------------------------------------------------------
__global__ __launch_bounds__(256, 2) void k_dist(
    const float* __restrict__ f, const double* __restrict__ sq,
    float* __restrict__ D, int b, int rowoff)
{
  __shared__ float As[2][32][132];   // [buf][c][r]
  __shared__ float Bs[2][32][132];   // [buf][c][m]
  int t = threadIdx.x;
  int nb = rowoff + blockIdx.x * 128;     // batch-local row base
  int mb = blockIdx.y * 128;              // batch-local col base
  const float* fb = f + (size_t)b * NPTS * CH;

  int lr = t & 127;          // staging row index
  int cq = (t >> 7) * 16;    // 16 channels per thread within a 32-chunk

  // stage chunk 0
#pragma unroll
  for (int i = 0; i < 4; ++i) {
    int c = cq + i * 4;
    float4 v = *(const float4*)&fb[(size_t)(nb + lr) * CH + c];
    As[0][c + 0][lr] = v.x; As[0][c + 1][lr] = v.y;
    As[0][c + 2][lr] = v.z; As[0][c + 3][lr] = v.w;
    float4 u = *(const float4*)&fb[(size_t)(mb + lr) * CH + c];
    Bs[0][c + 0][lr] = u.x; Bs[0][c + 1][lr] = u.y;
    Bs[0][c + 2][lr] = u.z; Bs[0][c + 3][lr] = u.w;
  }
  __syncthreads();

  int r0 = (t >> 4) * 8, m0 = (t & 15) * 8;
  double acc[8][8];
#pragma unroll
  for (int i = 0; i < 8; ++i)
#pragma unroll
    for (int j = 0; j < 8; ++j) acc[i][j] = 0.0;

#pragma unroll
  for (int ch = 0; ch < 4; ++ch) {
    int p = ch & 1;
    float4 pa[4], pb[4];
    if (ch < 3) {
      int cbase = (ch + 1) * 32;
#pragma unroll
      for (int i = 0; i < 4; ++i) {
        pa[i] = *(const float4*)&fb[(size_t)(nb + lr) * CH + cbase + cq + i * 4];
        pb[i] = *(const float4*)&fb[(size_t)(mb + lr) * CH + cbase + cq + i * 4];
      }
    }
#pragma unroll 4
    for (int kk = 0; kk < 32; ++kk) {
      float4 a0 = *(const float4*)&As[p][kk][r0];
      float4 a1 = *(const float4*)&As[p][kk][r0 + 4];
      float4 b0 = *(const float4*)&Bs[p][kk][m0];
      float4 b1 = *(const float4*)&Bs[p][kk][m0 + 4];
      double av[8] = {(double)a0.x, (double)a0.y, (double)a0.z, (double)a0.w,
                      (double)a1.x, (double)a1.y, (double)a1.z, (double)a1.w};
      double bv[8] = {(double)b0.x, (double)b0.y, (double)b0.z, (double)b0.w,
                      (double)b1.x, (double)b1.y, (double)b1.z, (double)b1.w};
#pragma unroll
      for (int i = 0; i < 8; ++i)
#pragma unroll
        for (int j = 0; j < 8; ++j) acc[i][j] = fma(av[i], bv[j], acc[i][j]);
    }
    if (ch < 3) {
      int q = p ^ 1;
#pragma unroll
      for (int i = 0; i < 4; ++i) {
        int c = cq + i * 4;
        As[q][c + 0][lr] = pa[i].x; As[q][c + 1][lr] = pa[i].y;
        As[q][c + 2][lr] = pa[i].z; As[q][c + 3][lr] = pa[i].w;
        Bs[q][c + 0][lr] = pb[i].x; Bs[q][c + 1][lr] = pb[i].y;
        Bs[q][c + 2][lr] = pb[i].z; Bs[q][c + 3][lr] = pb[i].w;
      }
    }
    __syncthreads();
  }

  double sqn[8], sqm[8];
#pragma unroll
  for (int i = 0; i < 8; ++i) sqn[i] = sq[(size_t)b * NPTS + nb + r0 + i];
#pragma unroll
  for (int j = 0; j < 8; ++j) sqm[j] = sq[(size_t)b * NPTS + mb + m0 + j];
#pragma unroll
  for (int i = 0; i < 8; ++i) {
    int rloc = blockIdx.x * 128 + r0 + i;   // chunk-local row
    float4 o;
    o.x = (float)((sqn[i] + sqm[0]) - 2.0 * acc[i][0]);
    o.y = (float)((sqn[i] + sqm[1]) - 2.0 * acc[i][1]);
    o.z = (float)((sqn[i] + sqm[2]) - 2.0 * acc[i][2]);
    o.w = (float)((sqn[i] + sqm[3]) - 2.0 * acc[i][3]);
    *(float4*)&D[(size_t)rloc * NPTS + mb + m0] = o;
    o.x = (float)((sqn[i] + sqm[4]) - 2.0 * acc[i][4]);
    o.y = (float)((sqn[i] + sqm[5]) - 2.0 * acc[i][5]);
    o.z = (float)((sqn[i] + sqm[6]) - 2.0 * acc[i][6]);
    o.w = (float)((sqn[i] + sqm[7]) - 2.0 * acc[i][7]);
    *(float4*)&D[(size_t)rloc * NPTS + mb + m0 + 4] = o;
  }
}

// ---------------------------------------------------------------------------
// Kernel 6: radix-select exact top-32 + attention + std-over-K.
// [round-7: histogram via hybrid ballot-cluster counting — concentrated
//  buckets (passes 0-1, 64 lanes same address) resolve in <=4 leader
//  atomics/wave instead of 64 serialized RMWs; spread buckets fall back to
//  plain atomics (low contention). Histogram VALUES identical -> selection
//  bit-identical to rounds 1-6.]
// ---------------------------------------------------------------------------
__device__ __forceinline__ unsigned int sortkey(float x) {
  unsigned int u = __float_as_uint(x);
  return (u & 0x80000000u) ? ~u : (u | 0x80000000u);
}

__global__ __launch_bounds__(256) void k_select(
    const float* __restrict__ D, const float* __restrict__ f,
    const float* __restrict__ qk, float* __restrict__ sv,
    int b, int rowoff)
{
  __shared__ unsigned int keys[NPTS];      // 16 KB sortable keys
  __shared__ unsigned int hist[256];
  __shared__ unsigned int wsum[4];
  __shared__ unsigned int eqw[4];
  __shared__ unsigned int sh_bucket, sh_excl, nkept;
  __shared__ int   kept[KNN];
  __shared__ float qkl[CH];
  __shared__ float fc[CH];
  __shared__ float eng[KNN];

  int t = threadIdx.x;
  int row = rowoff + blockIdx.x;            // batch-local row
  const float* fb = f + (size_t)b * NPTS * CH;

  {
    const float4* Dp = (const float4*)(D + (size_t)blockIdx.x * NPTS);
#pragma unroll
    for (int i = 0; i < 4; ++i) {
      float4 v = Dp[t + 256 * i];
      uint4 u;
      u.x = sortkey(v.x); u.y = sortkey(v.y);
      u.z = sortkey(v.z); u.w = sortkey(v.w);
      ((uint4*)keys)[t + 256 * i] = u;
    }
  }
  if (t == 0) nkept = 0;
  if (t < 32) {
    ((float4*)qkl)[t] = ((const float4*)(qk + ((size_t)b * NPTS + row) * CH))[t];
  } else if (t < 64) {
    ((float4*)fc)[t - 32] = ((const float4*)(fb + (size_t)row * CH))[t - 32];
  }
  __syncthreads();

  // 4-pass 8-bit radix select: find exact key of rank KNN (1-based)
  unsigned int prefix = 0;
  unsigned int target = KNN;
  unsigned int cnt_less = 0;
  for (int pass = 0; pass < 4; ++pass) {
    int shift = 24 - pass * 8;
    hist[t] = 0;
    __syncthreads();
#pragma unroll
    for (int i = 0; i < 16; ++i) {
      unsigned int k = keys[t + 256 * i];
      bool m = (pass == 0) || ((k >> (shift + 8)) == prefix);
      unsigned int bidx = (k >> shift) & 255u;
      bool pm = m;
      // up to 4 ballot-cluster rounds (cheap when buckets concentrated)
#pragma unroll
      for (int it = 0; it < 4; ++it) {
        unsigned long long act = __ballot(pm);
        if (act == 0ull) break;
        int leader = (int)__ffsll((unsigned long long)act) - 1;
        unsigned int lb = __shfl(bidx, leader);
        bool same = pm && (bidx == lb);
        unsigned long long grp = __ballot(same);
        if ((t & 63) == leader)
          atomicAdd(&hist[lb], (unsigned int)__popcll(grp));
        pm = pm && !same;
      }
      // spread remainder: plain atomics, low contention by construction
      if (pm) atomicAdd(&hist[bidx], 1u);
    }
    __syncthreads();
    unsigned int v = hist[t];
    unsigned int sc = v;
#pragma unroll
    for (int d = 1; d < 64; d <<= 1) {
      unsigned int nn = __shfl_up(sc, d);
      if ((t & 63) >= d) sc += nn;
    }
    if ((t & 63) == 63) wsum[t >> 6] = sc;
    __syncthreads();
    unsigned int wo = 0;
#pragma unroll
    for (int w = 0; w < 4; ++w) wo += (w < (t >> 6)) ? wsum[w] : 0u;
    unsigned int incl = sc + wo;
    unsigned int excl = incl - v;
    if (excl < target && target <= incl) { sh_bucket = (unsigned int)t; sh_excl = excl; }
    __syncthreads();
    prefix = (prefix << 8) | sh_bucket;
    target -= sh_excl;
    cnt_less += sh_excl;
    __syncthreads();
  }
  unsigned int thr_key = prefix;

  // compact strictly-less (arbitrary slot order; set semantics)
#pragma unroll
  for (int i = 0; i < 16; ++i) {
    int idx = t + 256 * i;
    if (keys[idx] < thr_key) {
      unsigned int p = atomicAdd(&nkept, 1u);
      kept[p] = idx;
    }
  }
  // fill remaining slots with ==thr_key elements in increasing index order
  {
    unsigned int eqloc = 0;
#pragma unroll
    for (int j = 0; j < 16; ++j)
      eqloc += (keys[t * 16 + ((j + t) & 15)] == thr_key) ? 1u : 0u;
    unsigned int esc = eqloc;
#pragma unroll
    for (int d = 1; d < 64; d <<= 1) {
      unsigned int nn = __shfl_up(esc, d);
      if ((t & 63) >= d) esc += nn;
    }
    if ((t & 63) == 63) eqw[t >> 6] = esc;
    __syncthreads();
    unsigned int ewo = 0;
#pragma unroll
    for (int w = 0; w < 4; ++w) ewo += (w < (t >> 6)) ? eqw[w] : 0u;
    unsigned int slot = cnt_less + (esc + ewo - eqloc);
#pragma unroll
    for (int j = 0; j < 16; ++j) {
      if (keys[t * 16 + j] == thr_key) {
        if (slot < KNN) kept[slot] = t * 16 + j;
        slot++;
      }
    }
  }
  __syncthreads();

  // energies: e_k = qk_n . (f_m - f_n) / sqrt(128)
  {
    int kk = t >> 3, lg = t & 7;
    int mg = kept[kk];
    const float* fm = fb + (size_t)mg * CH;
    float dd = 0.f, ds = 0.f;
#pragma unroll
    for (int i = 0; i < 4; ++i) {
      float4 qv = *(const float4*)&qkl[lg * 16 + i * 4];
      float4 vm = *(const float4*)&fm[lg * 16 + i * 4];
      float4 vc = *(const float4*)&fc[lg * 16 + i * 4];
      dd = fmaf(qv.x, vm.x, dd); dd = fmaf(qv.y, vm.y, dd);
      dd = fmaf(qv.z, vm.z, dd); dd = fmaf(qv.w, vm.w, dd);
      ds = fmaf(qv.x, vc.x, ds); ds = fmaf(qv.y, vc.y, ds);
      ds = fmaf(qv.z, vc.z, ds); ds = fmaf(qv.w, vc.w, ds);
    }
#pragma unroll
    for (int m = 1; m < 8; m <<= 1) { dd += __shfl_xor(dd, m); ds += __shfl_xor(ds, m); }
    if (lg == 0) eng[kk] = (dd - ds) * 0.08838834764831845f;
  }
  __syncthreads();

  // softmax over K + biased std over K (lanes 0..31 of wave 0)
  if (t < 64) {
    float e = (t < 32) ? eng[t] : -INFINITY;
    float mx = e;
#pragma unroll
    for (int m = 1; m < 32; m <<= 1) mx = fmaxf(mx, __shfl_xor(mx, m));
    float ex = (t < 32) ? expf(e - mx) : 0.f;
    float sm = ex;
#pragma unroll
    for (int m = 1; m < 32; m <<= 1) sm += __shfl_xor(sm, m);
    float a  = (t < 32) ? (ex / sm) : 0.f;
    float sa = a;
#pragma unroll
    for (int m = 1; m < 32; m <<= 1) sa += __shfl_xor(sa, m);
    float mean = sa * (1.f / 32.f);
    float dv = (t < 32) ? (a - mean) : 0.f;
    float vr = dv * dv;
#pragma unroll
    for (int m = 1; m < 32; m <<= 1) vr += __shfl_xor(vr, m);
    if (t == 0) sv[(size_t)b * NPTS + row] = sqrtf(vr * (1.f / 32.f));
  }
}

// ---------------------------------------------------------------------------
// Kernel 7: per-cloud standardize (ddof=1) + modified sigmoid; grid 8 x 256
// ---------------------------------------------------------------------------
__global__ __launch_bounds__(256) void k_final(const float* __restrict__ s,
                                               float* __restrict__ out)
{
  __shared__ float red[4];
  int b = blockIdx.x, t = threadIdx.x;
  const float4* sp = (const float4*)(s + (size_t)b * NPTS);
  float4* op = (float4*)(out + (size_t)b * NPTS);
  float4 vs[4];
  float loc = 0.f;
#pragma unroll
  for (int i = 0; i < 4; ++i) {
    vs[i] = sp[t + 256 * i];
    loc += vs[i].x + vs[i].y + vs[i].z + vs[i].w;
  }
#pragma unroll
  for (int sft = 1; sft < 64; sft <<= 1) loc += __shfl_xor(loc, sft);
  if ((t & 63) == 0) red[t >> 6] = loc;
  __syncthreads();
  float meanv = (red[0] + red[1] + red[2] + red[3]) * (1.f / 4096.f);
  __syncthreads();
  float loc2 = 0.f;
#pragma unroll
  for (int i = 0; i < 4; ++i) {
    float dx = vs[i].x - meanv, dy = vs[i].y - meanv;
    float dz = vs[i].z - meanv, dw = vs[i].w - meanv;
    loc2 += dx * dx + dy * dy + dz * dz + dw * dw;
  }
#pragma unroll
  for (int sft = 1; sft < 64; sft <<= 1) loc2 += __shfl_xor(loc2, sft);
  if ((t & 63) == 0) red[t >> 6] = loc2;
  __syncthreads();
  float var = (red[0] + red[1] + red[2] + red[3]) * (1.f / 4095.f);
  float rstd = rsqrtf(var);
  const float L20 = 4.3219280948873623f;  // log2(20)
#pragma unroll
  for (int i = 0; i < 4; ++i) {
    float4 v = vs[i], o;
    o.x = 1.f / (1.f + exp2f(-(v.x - meanv) * rstd * L20));
    o.y = 1.f / (1.f + exp2f(-(v.y - meanv) * rstd * L20));
    o.z = 1.f / (1.f + exp2f(-(v.z - meanv) * rstd * L20));
    o.w = 1.f / (1.f + exp2f(-(v.w - meanv) * rstd * L20));
    op[t + 256 * i] = o;
  }
}

// ---------------------------------------------------------------------------
extern "C" void kernel_launch(void* const* d_in, const int* in_sizes, int n_in,
                              void* d_out, int out_size, void* d_ws, size_t ws_size,
                              hipStream_t stream)
{
  const float* x     = (const float*)d_in[0];
  const float* W1    = (const float*)d_in[1];
  const float* gamma = (const float*)d_in[2];
  const float* beta  = (const float*)d_in[3];
  const float* bmean = (const float*)d_in[4];
  const float* bvar  = (const float*)d_in[5];
  const float* Wq    = (const float*)d_in[6];
  const float* Wk    = (const float*)d_in[7];
  float* out = (float*)d_out;

  float*  f   = (float*)d_ws;                               // 16 MB
  float*  qk  = f  + (size_t)B_ * NPTS * CH;                // 16 MB
  double* sqd = (double*)(qk + (size_t)B_ * NPTS * CH);     // 256 KB (f64)
  float*  sv  = (float*)(sqd + (size_t)B_ * NPTS);          // 128 KB
  float*  M   = sv + (size_t)B_ * NPTS;                     // 64 KB
  float*  D   = M  + (size_t)CH * CH;                       // chunk*4096*4 B

  // pick the largest chunk that fits the workspace (deterministic: ws_size
  // is constant across calls). 4096 -> 64 MB D; 2048 -> 32 MB; 1024 -> 16 MB.
  size_t fixed_bytes = (size_t)((char*)D - (char*)d_ws);
  size_t avail = (ws_size > fixed_bytes) ? (ws_size - fixed_bytes) : 0;
  int chunk = 1024;
  if (avail >= (size_t)4096 * NPTS * 4) chunk = 4096;
  else if (avail >= (size_t)2048 * NPTS * 4) chunk = 2048;

  hipLaunchKernelGGL(k_conv_bn, dim3(1024), dim3(256), 0, stream,
                     x, W1, gamma, beta, bmean, bvar, f);
  hipLaunchKernelGGL(k_sq, dim3(8192), dim3(256), 0, stream, f, sqd);
  hipLaunchKernelGGL(k_wqk, dim3(8, 8), dim3(256), 0, stream, Wq, Wk, M);
  hipLaunchKernelGGL(k_qk, dim3(512), dim3(256), 0, stream, f, M, qk);
  for (int b = 0; b < B_; ++b) {
    for (int ro = 0; ro < NPTS; ro += chunk) {
      hipLaunchKernelGGL(k_dist, dim3(chunk / 128, 32), dim3(256), 0, stream,
                         f, sqd, D, b, ro);
      hipLaunchKernelGGL(k_select, dim3(chunk), dim3(256), 0, stream,
                         D, f, qk, sv, b, ro);
    }
  }
  hipLaunchKernelGGL(k_final, dim3(8), dim3(256), 0, stream, sv, out);
}

// Round 9
// 1748.849 us; speedup vs baseline: 1.2146x; 1.0981x over previous
//
#include <hip/hip_runtime.h>
#include <math.h>

#define B_   8
#define CIN  1152
#define NPTS 4096
#define CH   128
#define KNN  32

// ---------------------------------------------------------------------------
// Kernel 1: 1x1 conv (W1 @ x) in FP64 vector + BN(inference, f64) + LeakyReLU
// f = (float)f64. [round-4 verbatim — best measured conv: 310 µs, VALUBusy 66.
// f64-LDS variants (r5/r6) were slower: LDS-pipe-bound. cvt tax stays.]
// NOTE: v_mfma_f64 is broken/absent on gfx950 (round-2 evidence) — no MFMA.
// ---------------------------------------------------------------------------
__global__ __launch_bounds__(256) void k_conv_bn(
    const float* __restrict__ x, const float* __restrict__ W1,
    const float* __restrict__ gamma, const float* __restrict__ beta,
    const float* __restrict__ bmean, const float* __restrict__ bvar,
    float* __restrict__ f)
{
  __shared__ float Wl[8][132];   // [k][c]
  __shared__ float Xl[8][36];    // [k][n]
  int bid = blockIdx.x;
  int b = bid & 7;
  int nbase = (bid >> 3) * 32;
  int t = threadIdx.x;
  int c0 = (t & 31) * 4, n0 = (t >> 5) * 4;
  double acc[4][4];
#pragma unroll
  for (int i = 0; i < 4; ++i)
#pragma unroll
    for (int j = 0; j < 4; ++j) acc[i][j] = 0.0;

  for (int k0 = 0; k0 < CIN; k0 += 8) {
    {
      int c = t >> 1, kp = (t & 1) * 4;
      float4 w4 = *(const float4*)&W1[(size_t)c * CIN + k0 + kp];
      Wl[kp + 0][c] = w4.x; Wl[kp + 1][c] = w4.y;
      Wl[kp + 2][c] = w4.z; Wl[kp + 3][c] = w4.w;
    }
    {
      int k = t >> 5, n = t & 31;
      Xl[k][n] = x[((size_t)b * CIN + (k0 + k)) * NPTS + nbase + n];
    }
    __syncthreads();
#pragma unroll
    for (int kk = 0; kk < 8; ++kk) {
      float4 a  = *(const float4*)&Wl[kk][c0];
      float4 b0 = *(const float4*)&Xl[kk][n0];
      double av[4] = {(double)a.x, (double)a.y, (double)a.z, (double)a.w};
      double bv[4] = {(double)b0.x, (double)b0.y, (double)b0.z, (double)b0.w};
#pragma unroll
      for (int i = 0; i < 4; ++i)
#pragma unroll
        for (int j = 0; j < 4; ++j) acc[i][j] = fma(av[i], bv[j], acc[i][j]);
    }
    __syncthreads();
  }
  double rs[4], gm[4], bt[4], mu[4];
#pragma unroll
  for (int i = 0; i < 4; ++i) {
    int c = c0 + i;
    rs[i] = 1.0 / sqrt((double)bvar[c] + 1e-5);
    gm[i] = (double)gamma[c]; bt[i] = (double)beta[c]; mu[i] = (double)bmean[c];
  }
#pragma unroll
  for (int j = 0; j < 4; ++j) {
    int n = nbase + n0 + j;
    float4 o;
    float* op = &o.x;
#pragma unroll
    for (int i = 0; i < 4; ++i) {
      double v = (acc[i][j] - mu[i]) * rs[i];
      v = v * gm[i] + bt[i];
      if (v < 0.0) v = 0.2 * v;
      op[i] = (float)v;
    }
    *(float4*)&f[((size_t)b * NPTS + n) * CH + c0] = o;
  }
}

// ---------------------------------------------------------------------------
// Kernel 2: sq[row] = sum_c f[row][c]^2 — FP64-EXACT (feeds exact dist).
// ---------------------------------------------------------------------------
__global__ __launch_bounds__(256) void k_sq(const float* __restrict__ f,
                                            double* __restrict__ sq)
{
  int row = blockIdx.x * 4 + (threadIdx.x >> 6);
  int lane = threadIdx.x & 63;
  float2 v = ((const float2*)f)[(size_t)row * 64 + lane];
  double s = (double)v.x * (double)v.x + (double)v.y * (double)v.y;
#pragma unroll
  for (int sft = 1; sft < 64; sft <<= 1) s += __shfl_xor(s, sft);
  if (lane == 0) sq[row] = s;
}

// ---------------------------------------------------------------------------
// Kernel 3: M[c][c'] = sum_o Wq[o][c] * Wk[o][c'] ; grid (8,8) x 256
// ---------------------------------------------------------------------------
__global__ __launch_bounds__(256) void k_wqk(const float* __restrict__ Wq,
                                             const float* __restrict__ Wk,
                                             float* __restrict__ M)
{
  __shared__ float Ql[128][17];
  __shared__ float Kl[128][17];
  int t = threadIdx.x;
  int cb = blockIdx.x * 16;
  int db = blockIdx.y * 16;
  {
    int o = t >> 1, h = (t & 1) * 8;
    float4 a = *(const float4*)&Wq[(size_t)o * CH + cb + h];
    float4 b = *(const float4*)&Wq[(size_t)o * CH + cb + h + 4];
    Ql[o][h + 0] = a.x; Ql[o][h + 1] = a.y; Ql[o][h + 2] = a.z; Ql[o][h + 3] = a.w;
    Ql[o][h + 4] = b.x; Ql[o][h + 5] = b.y; Ql[o][h + 6] = b.z; Ql[o][h + 7] = b.w;
    float4 c4 = *(const float4*)&Wk[(size_t)o * CH + db + h];
    float4 d4 = *(const float4*)&Wk[(size_t)o * CH + db + h + 4];
    Kl[o][h + 0] = c4.x; Kl[o][h + 1] = c4.y; Kl[o][h + 2] = c4.z; Kl[o][h + 3] = c4.w;
    Kl[o][h + 4] = d4.x; Kl[o][h + 5] = d4.y; Kl[o][h + 6] = d4.z; Kl[o][h + 7] = d4.w;
  }
  __syncthreads();
  int ci = t >> 4, cj = t & 15;
  float acc = 0.f;
#pragma unroll 8
  for (int o = 0; o < 128; ++o) acc = fmaf(Ql[o][ci], Kl[o][cj], acc);
  M[(size_t)(cb + ci) * CH + db + cj] = acc;
}

// ---------------------------------------------------------------------------
// Kernel 4: qk = f @ M  ([32768 x 128] x [128 x 128]) ; grid 512 x 256
// ---------------------------------------------------------------------------
__global__ __launch_bounds__(256) void k_qk(const float* __restrict__ f,
                                            const float* __restrict__ M,
                                            float* __restrict__ qk)
{
  __shared__ float Ft[128][68];      // [k][r], 64 rows
  __shared__ float Ml[128 * 128];    // [k][c']
  int t = threadIdx.x;
  size_t rbase = (size_t)blockIdx.x * 64;
  {
    int r = t & 63, cp = (t >> 6) * 32;
    for (int i = 0; i < 8; ++i) {
      int c = cp + i * 4;
      float4 v = *(const float4*)&f[(rbase + r) * CH + c];
      Ft[c][r] = v.x; Ft[c + 1][r] = v.y; Ft[c + 2][r] = v.z; Ft[c + 3][r] = v.w;
    }
  }
  {
    const float4* Mg = (const float4*)M;
    float4* Md = (float4*)Ml;
    for (int i = 0; i < 16; ++i) Md[t + 256 * i] = Mg[t + 256 * i];
  }
  __syncthreads();
  int r0 = (t >> 4) * 4, c0 = (t & 15) * 8;
  float acc[4][8];
#pragma unroll
  for (int i = 0; i < 4; ++i)
#pragma unroll
    for (int j = 0; j < 8; ++j) acc[i][j] = 0.f;
#pragma unroll 8
  for (int k = 0; k < 128; ++k) {
    float4 a  = *(const float4*)&Ft[k][r0];
    float4 b0 = *(const float4*)&Ml[k * 128 + c0];
    float4 b1 = *(const float4*)&Ml[k * 128 + c0 + 4];
    float av[4] = {a.x, a.y, a.z, a.w};
    float bv[8] = {b0.x, b0.y, b0.z, b0.w, b1.x, b1.y, b1.z, b1.w};
#pragma unroll
    for (int i = 0; i < 4; ++i)
#pragma unroll
      for (int j = 0; j < 8; ++j) acc[i][j] = fmaf(av[i], bv[j], acc[i][j]);
  }
#pragma unroll
  for (int i = 0; i < 4; ++i) {
    float4 o0 = {acc[i][0], acc[i][1], acc[i][2], acc[i][3]};
    float4 o1 = {acc[i][4], acc[i][5], acc[i][6], acc[i][7]};
    *(float4*)&qk[(rbase + r0 + i) * CH + c0]     = o0;
    *(float4*)&qk[(rbase + r0 + i) * CH + c0 + 4] = o1;
  }
}

// ---------------------------------------------------------------------------
// Kernel 5a: SYMMETRIC distance GEMM (full-batch D only). D is bit-exactly
// symmetric (same ascending-k f64 fma chain both orientations; mult/add
// commute exactly) -> compute only the 528 upper tiles (bx<=by), mirror
// off-diagonal tiles via LDS transpose (T overlays As+Bs: identical 16896-
// float footprint; XOR-by-(t&3) column swizzle keeps T-writes 4-way).
// Values bit-identical to the rectangular kernel.
// ---------------------------------------------------------------------------
#define DTS 132
__global__ __launch_bounds__(256, 2) void k_dist_sym(
    const float* __restrict__ f, const double* __restrict__ sq,
    float* __restrict__ D, int b)
{
  __shared__ float smem[16896];            // As(2x32x132) + Bs(2x32x132) = T(128x132)
  float* As = smem;                        // As[p][c][r] = smem[(p*32+c)*132+r]
  float* Bs = smem + 2 * 32 * DTS;         // same layout
  int t = threadIdx.x;
  int id = blockIdx.x;
  int by = (int)((sqrtf(8.f * id + 1.f) - 1.f) * 0.5f);
  while ((by + 1) * (by + 2) / 2 <= id) ++by;
  while (by * (by + 1) / 2 > id) --by;
  int bx = id - by * (by + 1) / 2;         // bx <= by
  int nb = bx * 128, mb = by * 128;
  const float* fb = f + (size_t)b * NPTS * CH;

  int lr = t & 127;          // staging row index
  int cq = (t >> 7) * 16;    // 16 channels per thread within a 32-chunk

  // stage chunk 0
#pragma unroll
  for (int i = 0; i < 4; ++i) {
    int c = cq + i * 4;
    float4 v = *(const float4*)&fb[(size_t)(nb + lr) * CH + c];
    As[(c + 0) * DTS + lr] = v.x; As[(c + 1) * DTS + lr] = v.y;
    As[(c + 2) * DTS + lr] = v.z; As[(c + 3) * DTS + lr] = v.w;
    float4 u = *(const float4*)&fb[(size_t)(mb + lr) * CH + c];
    Bs[(c + 0) * DTS + lr] = u.x; Bs[(c + 1) * DTS + lr] = u.y;
    Bs[(c + 2) * DTS + lr] = u.z; Bs[(c + 3) * DTS + lr] = u.w;
  }
  __syncthreads();

  int r0 = (t >> 4) * 8, m0 = (t & 15) * 8;
  double acc[8][8];
#pragma unroll
  for (int i = 0; i < 8; ++i)
#pragma unroll
    for (int j = 0; j < 8; ++j) acc[i][j] = 0.0;

#pragma unroll
  for (int ch = 0; ch < 4; ++ch) {
    int p = ch & 1;
    float4 pa[4], pb[4];
    if (ch < 3) {
      int cbase = (ch + 1) * 32;
#pragma unroll
      for (int i = 0; i < 4; ++i) {
        pa[i] = *(const float4*)&fb[(size_t)(nb + lr) * CH + cbase + cq + i * 4];
        pb[i] = *(const float4*)&fb[(size_t)(mb + lr) * CH + cbase + cq + i * 4];
      }
    }
#pragma unroll 4
    for (int kk = 0; kk < 32; ++kk) {
      const float* Ap = &As[(p * 32 + kk) * DTS];
      const float* Bp = &Bs[(p * 32 + kk) * DTS];
      float4 a0 = *(const float4*)&Ap[r0];
      float4 a1 = *(const float4*)&Ap[r0 + 4];
      float4 b0 = *(const float4*)&Bp[m0];
      float4 b1 = *(const float4*)&Bp[m0 + 4];
      double av[8] = {(double)a0.x, (double)a0.y, (double)a0.z, (double)a0.w,
                      (double)a1.x, (double)a1.y, (double)a1.z, (double)a1.w};
      double bv[8] = {(double)b0.x, (double)b0.y, (double)b0.z, (double)b0.w,
                      (double)b1.x, (double)b1.y, (double)b1.z, (double)b1.w};
#pragma unroll
      for (int i = 0; i < 8; ++i)
#pragma unroll
        for (int j = 0; j < 8; ++j) acc[i][j] = fma(av[i], bv[j], acc[i][j]);
    }
    if (ch < 3) {
      int q = p ^ 1;
#pragma unroll
      for (int i = 0; i < 4; ++i) {
        int c = cq + i * 4;
        As[(q * 32 + c + 0) * DTS + lr] = pa[i].x; As[(q * 32 + c + 1) * DTS + lr] = pa[i].y;
        As[(q * 32 + c + 2) * DTS + lr] = pa[i].z; As[(q * 32 + c + 3) * DTS + lr] = pa[i].w;
        Bs[(q * 32 + c + 0) * DTS + lr] = pb[i].x; Bs[(q * 32 + c + 1) * DTS + lr] = pb[i].y;
        Bs[(q * 32 + c + 2) * DTS + lr] = pb[i].z; Bs[(q * 32 + c + 3) * DTS + lr] = pb[i].w;
      }
    }
    __syncthreads();     // after last iter: all compute done, LDS free for T
  }

  double sqn[8], sqm[8];
#pragma unroll
  for (int i = 0; i < 8; ++i) sqn[i] = sq[(size_t)b * NPTS + nb + r0 + i];
#pragma unroll
  for (int j = 0; j < 8; ++j) sqm[j] = sq[(size_t)b * NPTS + mb + m0 + j];

  int xk = (t & 3) * 8;    // T column swizzle key (per-thread constant)
#pragma unroll
  for (int i = 0; i < 8; ++i) {
    float vr[8];
#pragma unroll
    for (int j = 0; j < 8; ++j) {
      vr[j] = (float)((sqn[i] + sqm[j]) - 2.0 * acc[i][j]);
      if (bx != by) smem[(m0 + j) * DTS + ((r0 + i) ^ xk)] = vr[j];
    }
    float4 o0 = {vr[0], vr[1], vr[2], vr[3]};
    float4 o1 = {vr[4], vr[5], vr[6], vr[7]};
    *(float4*)&D[(size_t)(nb + r0 + i) * NPTS + mb + m0]     = o0;
    *(float4*)&D[(size_t)(nb + r0 + i) * NPTS + mb + m0 + 4] = o1;
  }

  if (bx != by) {
    __syncthreads();
    // mirrored store: rows mb+rr, cols nb.. (coalesced 512B per 16 lanes)
#pragma unroll
    for (int ph = 0; ph < 8; ++ph) {
      int rr = ph * 16 + (t >> 4);
      int cc = (t & 15) * 8;
      int xr = ((rr >> 3) & 3) * 8;
      float4 s0 = *(const float4*)&smem[rr * DTS + (cc ^ xr)];
      float4 s1 = *(const float4*)&smem[rr * DTS + ((cc + 4) ^ xr)];
      *(float4*)&D[(size_t)(mb + rr) * NPTS + nb + cc]     = s0;
      *(float4*)&D[(size_t)(mb + rr) * NPTS + nb + cc + 4] = s1;
    }
  }
}

// ---------------------------------------------------------------------------
// Kernel 5b: rectangular distance GEMM [round-4 verbatim] — fallback for
// chunk < 4096 (workspace-limited), where D is not full-batch.
// ---------------------------------------------------------------------------
__global__ __launch_bounds__(256, 2) void k_dist(
    const float* __restrict__ f, const double* __restrict__ sq,
    float* __restrict__ D, int b, int rowoff)
{
  __shared__ float As[2][32][132];   // [buf][c][r]
  __shared__ float Bs[2][32][132];   // [buf][c][m]
  int t = threadIdx.x;
  int nb = rowoff + blockIdx.x * 128;     // batch-local row base
  int mb = blockIdx.y * 128;              // batch-local col base
  const float* fb = f + (size_t)b * NPTS * CH;

  int lr = t & 127;          // staging row index
  int cq = (t >> 7) * 16;    // 16 channels per thread within a 32-chunk

#pragma unroll
  for (int i = 0; i < 4; ++i) {
    int c = cq + i * 4;
    float4 v = *(const float4*)&fb[(size_t)(nb + lr) * CH + c];
    As[0][c + 0][lr] = v.x; As[0][c + 1][lr] = v.y;
    As[0][c + 2][lr] = v.z; As[0][c + 3][lr] = v.w;
    float4 u = *(const float4*)&fb[(size_t)(mb + lr) * CH + c];
    Bs[0][c + 0][lr] = u.x; Bs[0][c + 1][lr] = u.y;
    Bs[0][c + 2][lr] = u.z; Bs[0][c + 3][lr] = u.w;
  }
  __syncthreads();

  int r0 = (t >> 4) * 8, m0 = (t & 15) * 8;
  double acc[8][8];
#pragma unroll
  for (int i = 0; i < 8; ++i)
#pragma unroll
    for (int j = 0; j < 8; ++j) acc[i][j] = 0.0;

#pragma unroll
  for (int ch = 0; ch < 4; ++ch) {
    int p = ch & 1;
    float4 pa[4], pb[4];
    if (ch < 3) {
      int cbase = (ch + 1) * 32;
#pragma unroll
      for (int i = 0; i < 4; ++i) {
        pa[i] = *(const float4*)&fb[(size_t)(nb + lr) * CH + cbase + cq + i * 4];
        pb[i] = *(const float4*)&fb[(size_t)(mb + lr) * CH + cbase + cq + i * 4];
      }
    }
#pragma unroll 4
    for (int kk = 0; kk < 32; ++kk) {
      float4 a0 = *(const float4*)&As[p][kk][r0];
      float4 a1 = *(const float4*)&As[p][kk][r0 + 4];
      float4 b0 = *(const float4*)&Bs[p][kk][m0];
      float4 b1 = *(const float4*)&Bs[p][kk][m0 + 4];
      double av[8] = {(double)a0.x, (double)a0.y, (double)a0.z, (double)a0.w,
                      (double)a1.x, (double)a1.y, (double)a1.z, (double)a1.w};
      double bv[8] = {(double)b0.x, (double)b0.y, (double)b0.z, (double)b0.w,
                      (double)b1.x, (double)b1.y, (double)b1.z, (double)b1.w};
#pragma unroll
      for (int i = 0; i < 8; ++i)
#pragma unroll
        for (int j = 0; j < 8; ++j) acc[i][j] = fma(av[i], bv[j], acc[i][j]);
    }
    if (ch < 3) {
      int q = p ^ 1;
#pragma unroll
      for (int i = 0; i < 4; ++i) {
        int c = cq + i * 4;
        As[q][c + 0][lr] = pa[i].x; As[q][c + 1][lr] = pa[i].y;
        As[q][c + 2][lr] = pa[i].z; As[q][c + 3][lr] = pa[i].w;
        Bs[q][c + 0][lr] = pb[i].x; Bs[q][c + 1][lr] = pb[i].y;
        Bs[q][c + 2][lr] = pb[i].z; Bs[q][c + 3][lr] = pb[i].w;
      }
    }
    __syncthreads();
  }

  double sqn[8], sqm[8];
#pragma unroll
  for (int i = 0; i < 8; ++i) sqn[i] = sq[(size_t)b * NPTS + nb + r0 + i];
#pragma unroll
  for (int j = 0; j < 8; ++j) sqm[j] = sq[(size_t)b * NPTS + mb + m0 + j];
#pragma unroll
  for (int i = 0; i < 8; ++i) {
    int rloc = blockIdx.x * 128 + r0 + i;   // chunk-local row
    float4 o;
    o.x = (float)((sqn[i] + sqm[0]) - 2.0 * acc[i][0]);
    o.y = (float)((sqn[i] + sqm[1]) - 2.0 * acc[i][1]);
    o.z = (float)((sqn[i] + sqm[2]) - 2.0 * acc[i][2]);
    o.w = (float)((sqn[i] + sqm[3]) - 2.0 * acc[i][3]);
    *(float4*)&D[(size_t)rloc * NPTS + mb + m0] = o;
    o.x = (float)((sqn[i] + sqm[4]) - 2.0 * acc[i][4]);
    o.y = (float)((sqn[i] + sqm[5]) - 2.0 * acc[i][5]);
    o.z = (float)((sqn[i] + sqm[6]) - 2.0 * acc[i][6]);
    o.w = (float)((sqn[i] + sqm[7]) - 2.0 * acc[i][7]);
    *(float4*)&D[(size_t)rloc * NPTS + mb + m0 + 4] = o;
  }
}

// ---------------------------------------------------------------------------
// Kernel 6: radix-select exact top-32 + attention + std-over-K.
// [round-7 verbatim: ballot-cluster histogram]
// ---------------------------------------------------------------------------
__device__ __forceinline__ unsigned int sortkey(float x) {
  unsigned int u = __float_as_uint(x);
  return (u & 0x80000000u) ? ~u : (u | 0x80000000u);
}

__global__ __launch_bounds__(256) void k_select(
    const float* __restrict__ D, const float* __restrict__ f,
    const float* __restrict__ qk, float* __restrict__ sv,
    int b, int rowoff)
{
  __shared__ unsigned int keys[NPTS];      // 16 KB sortable keys
  __shared__ unsigned int hist[256];
  __shared__ unsigned int wsum[4];
  __shared__ unsigned int eqw[4];
  __shared__ unsigned int sh_bucket, sh_excl, nkept;
  __shared__ int   kept[KNN];
  __shared__ float qkl[CH];
  __shared__ float fc[CH];
  __shared__ float eng[KNN];

  int t = threadIdx.x;
  int row = rowoff + blockIdx.x;            // batch-local row
  const float* fb = f + (size_t)b * NPTS * CH;

  {
    const float4* Dp = (const float4*)(D + (size_t)blockIdx.x * NPTS);
#pragma unroll
    for (int i = 0; i < 4; ++i) {
      float4 v = Dp[t + 256 * i];
      uint4 u;
      u.x = sortkey(v.x); u.y = sortkey(v.y);
      u.z = sortkey(v.z); u.w = sortkey(v.w);
      ((uint4*)keys)[t + 256 * i] = u;
    }
  }
  if (t == 0) nkept = 0;
  if (t < 32) {
    ((float4*)qkl)[t] = ((const float4*)(qk + ((size_t)b * NPTS + row) * CH))[t];
  } else if (t < 64) {
    ((float4*)fc)[t - 32] = ((const float4*)(fb + (size_t)row * CH))[t - 32];
  }
  __syncthreads();

  // 4-pass 8-bit radix select: find exact key of rank KNN (1-based)
  unsigned int prefix = 0;
  unsigned int target = KNN;
  unsigned int cnt_less = 0;
  for (int pass = 0; pass < 4; ++pass) {
    int shift = 24 - pass * 8;
    hist[t] = 0;
    __syncthreads();
#pragma unroll
    for (int i = 0; i < 16; ++i) {
      unsigned int k = keys[t + 256 * i];
      bool m = (pass == 0) || ((k >> (shift + 8)) == prefix);
      unsigned int bidx = (k >> shift) & 255u;
      bool pm = m;
#pragma unroll
      for (int it = 0; it < 4; ++it) {
        unsigned long long act = __ballot(pm);
        if (act == 0ull) break;
        int leader = (int)__ffsll((unsigned long long)act) - 1;
        unsigned int lb = __shfl(bidx, leader);
        bool same = pm && (bidx == lb);
        unsigned long long grp = __ballot(same);
        if ((t & 63) == leader)
          atomicAdd(&hist[lb], (unsigned int)__popcll(grp));
        pm = pm && !same;
      }
      if (pm) atomicAdd(&hist[bidx], 1u);
    }
    __syncthreads();
    unsigned int v = hist[t];
    unsigned int sc = v;
#pragma unroll
    for (int d = 1; d < 64; d <<= 1) {
      unsigned int nn = __shfl_up(sc, d);
      if ((t & 63) >= d) sc += nn;
    }
    if ((t & 63) == 63) wsum[t >> 6] = sc;
    __syncthreads();
    unsigned int wo = 0;
#pragma unroll
    for (int w = 0; w < 4; ++w) wo += (w < (t >> 6)) ? wsum[w] : 0u;
    unsigned int incl = sc + wo;
    unsigned int excl = incl - v;
    if (excl < target && target <= incl) { sh_bucket = (unsigned int)t; sh_excl = excl; }
    __syncthreads();
    prefix = (prefix << 8) | sh_bucket;
    target -= sh_excl;
    cnt_less += sh_excl;
    __syncthreads();
  }
  unsigned int thr_key = prefix;

  // compact strictly-less (arbitrary slot order; set semantics)
#pragma unroll
  for (int i = 0; i < 16; ++i) {
    int idx = t + 256 * i;
    if (keys[idx] < thr_key) {
      unsigned int p = atomicAdd(&nkept, 1u);
      kept[p] = idx;
    }
  }
  // fill remaining slots with ==thr_key elements in increasing index order
  {
    unsigned int eqloc = 0;
#pragma unroll
    for (int j = 0; j < 16; ++j)
      eqloc += (keys[t * 16 + ((j + t) & 15)] == thr_key) ? 1u : 0u;
    unsigned int esc = eqloc;
#pragma unroll
    for (int d = 1; d < 64; d <<= 1) {
      unsigned int nn = __shfl_up(esc, d);
      if ((t & 63) >= d) esc += nn;
    }
    if ((t & 63) == 63) eqw[t >> 6] = esc;
    __syncthreads();
    unsigned int ewo = 0;
#pragma unroll
    for (int w = 0; w < 4; ++w) ewo += (w < (t >> 6)) ? eqw[w] : 0u;
    unsigned int slot = cnt_less + (esc + ewo - eqloc);
#pragma unroll
    for (int j = 0; j < 16; ++j) {
      if (keys[t * 16 + j] == thr_key) {
        if (slot < KNN) kept[slot] = t * 16 + j;
        slot++;
      }
    }
  }
  __syncthreads();

  // energies: e_k = qk_n . (f_m - f_n) / sqrt(128)
  {
    int kk = t >> 3, lg = t & 7;
    int mg = kept[kk];
    const float* fm = fb + (size_t)mg * CH;
    float dd = 0.f, ds = 0.f;
#pragma unroll
    for (int i = 0; i < 4; ++i) {
      float4 qv = *(const float4*)&qkl[lg * 16 + i * 4];
      float4 vm = *(const float4*)&fm[lg * 16 + i * 4];
      float4 vc = *(const float4*)&fc[lg * 16 + i * 4];
      dd = fmaf(qv.x, vm.x, dd); dd = fmaf(qv.y, vm.y, dd);
      dd = fmaf(qv.z, vm.z, dd); dd = fmaf(qv.w, vm.w, dd);
      ds = fmaf(qv.x, vc.x, ds); ds = fmaf(qv.y, vc.y, ds);
      ds = fmaf(qv.z, vc.z, ds); ds = fmaf(qv.w, vc.w, ds);
    }
#pragma unroll
    for (int m = 1; m < 8; m <<= 1) { dd += __shfl_xor(dd, m); ds += __shfl_xor(ds, m); }
    if (lg == 0) eng[kk] = (dd - ds) * 0.08838834764831845f;
  }
  __syncthreads();

  // softmax over K + biased std over K (lanes 0..31 of wave 0)
  if (t < 64) {
    float e = (t < 32) ? eng[t] : -INFINITY;
    float mx = e;
#pragma unroll
    for (int m = 1; m < 32; m <<= 1) mx = fmaxf(mx, __shfl_xor(mx, m));
    float ex = (t < 32) ? expf(e - mx) : 0.f;
    float sm = ex;
#pragma unroll
    for (int m = 1; m < 32; m <<= 1) sm += __shfl_xor(sm, m);
    float a  = (t < 32) ? (ex / sm) : 0.f;
    float sa = a;
#pragma unroll
    for (int m = 1; m < 32; m <<= 1) sa += __shfl_xor(sa, m);
    float mean = sa * (1.f / 32.f);
    float dv = (t < 32) ? (a - mean) : 0.f;
    float vr = dv * dv;
#pragma unroll
    for (int m = 1; m < 32; m <<= 1) vr += __shfl_xor(vr, m);
    if (t == 0) sv[(size_t)b * NPTS + row] = sqrtf(vr * (1.f / 32.f));
  }
}

// ---------------------------------------------------------------------------
// Kernel 7: per-cloud standardize (ddof=1) + modified sigmoid; grid 8 x 256
// ---------------------------------------------------------------------------
__global__ __launch_bounds__(256) void k_final(const float* __restrict__ s,
                                               float* __restrict__ out)
{
  __shared__ float red[4];
  int b = blockIdx.x, t = threadIdx.x;
  const float4* sp = (const float4*)(s + (size_t)b * NPTS);
  float4* op = (float4*)(out + (size_t)b * NPTS);
  float4 vs[4];
  float loc = 0.f;
#pragma unroll
  for (int i = 0; i < 4; ++i) {
    vs[i] = sp[t + 256 * i];
    loc += vs[i].x + vs[i].y + vs[i].z + vs[i].w;
  }
#pragma unroll
  for (int sft = 1; sft < 64; sft <<= 1) loc += __shfl_xor(loc, sft);
  if ((t & 63) == 0) red[t >> 6] = loc;
  __syncthreads();
  float meanv = (red[0] + red[1] + red[2] + red[3]) * (1.f / 4096.f);
  __syncthreads();
  float loc2 = 0.f;
#pragma unroll
  for (int i = 0; i < 4; ++i) {
    float dx = vs[i].x - meanv, dy = vs[i].y - meanv;
    float dz = vs[i].z - meanv, dw = vs[i].w - meanv;
    loc2 += dx * dx + dy * dy + dz * dz + dw * dw;
  }
#pragma unroll
  for (int sft = 1; sft < 64; sft <<= 1) loc2 += __shfl_xor(loc2, sft);
  if ((t & 63) == 0) red[t >> 6] = loc2;
  __syncthreads();
  float var = (red[0] + red[1] + red[2] + red[3]) * (1.f / 4095.f);
  float rstd = rsqrtf(var);
  const float L20 = 4.3219280948873623f;  // log2(20)
#pragma unroll
  for (int i = 0; i < 4; ++i) {
    float4 v = vs[i], o;
    o.x = 1.f / (1.f + exp2f(-(v.x - meanv) * rstd * L20));
    o.y = 1.f / (1.f + exp2f(-(v.y - meanv) * rstd * L20));
    o.z = 1.f / (1.f + exp2f(-(v.z - meanv) * rstd * L20));
    o.w = 1.f / (1.f + exp2f(-(v.w - meanv) * rstd * L20));
    op[t + 256 * i] = o;
  }
}

// ---------------------------------------------------------------------------
extern "C" void kernel_launch(void* const* d_in, const int* in_sizes, int n_in,
                              void* d_out, int out_size, void* d_ws, size_t ws_size,
                              hipStream_t stream)
{
  const float* x     = (const float*)d_in[0];
  const float* W1    = (const float*)d_in[1];
  const float* gamma = (const float*)d_in[2];
  const float* beta  = (const float*)d_in[3];
  const float* bmean = (const float*)d_in[4];
  const float* bvar  = (const float*)d_in[5];
  const float* Wq    = (const float*)d_in[6];
  const float* Wk    = (const float*)d_in[7];
  float* out = (float*)d_out;

  float*  f   = (float*)d_ws;                               // 16 MB
  float*  qk  = f  + (size_t)B_ * NPTS * CH;                // 16 MB
  double* sqd = (double*)(qk + (size_t)B_ * NPTS * CH);     // 256 KB (f64)
  float*  sv  = (float*)(sqd + (size_t)B_ * NPTS);          // 128 KB
  float*  M   = sv + (size_t)B_ * NPTS;                     // 64 KB
  float*  D   = M  + (size_t)CH * CH;                       // chunk*4096*4 B

  // pick the largest chunk that fits the workspace (deterministic: ws_size
  // is constant across calls). 4096 -> 64 MB D; 2048 -> 32 MB; 1024 -> 16 MB.
  size_t fixed_bytes = (size_t)((char*)D - (char*)d_ws);
  size_t avail = (ws_size > fixed_bytes) ? (ws_size - fixed_bytes) : 0;
  int chunk = 1024;
  if (avail >= (size_t)4096 * NPTS * 4) chunk = 4096;
  else if (avail >= (size_t)2048 * NPTS * 4) chunk = 2048;

  hipLaunchKernelGGL(k_conv_bn, dim3(1024), dim3(256), 0, stream,
                     x, W1, gamma, beta, bmean, bvar, f);
  hipLaunchKernelGGL(k_sq, dim3(8192), dim3(256), 0, stream, f, sqd);
  hipLaunchKernelGGL(k_wqk, dim3(8, 8), dim3(256), 0, stream, Wq, Wk, M);
  hipLaunchKernelGGL(k_qk, dim3(512), dim3(256), 0, stream, f, M, qk);
  if (chunk == 4096) {
    // full-batch D: symmetric dist (528 upper tiles + mirrored stores)
    for (int b = 0; b < B_; ++b) {
      hipLaunchKernelGGL(k_dist_sym, dim3(528), dim3(256), 0, stream,
                         f, sqd, D, b);
      hipLaunchKernelGGL(k_select, dim3(4096), dim3(256), 0, stream,
                         D, f, qk, sv, b, 0);
    }
  } else {
    for (int b = 0; b < B_; ++b) {
      for (int ro = 0; ro < NPTS; ro += chunk) {
        hipLaunchKernelGGL(k_dist, dim3(chunk / 128, 32), dim3(256), 0, stream,
                           f, sqd, D, b, ro);
        hipLaunchKernelGGL(k_select, dim3(chunk), dim3(256), 0, stream,
                           D, f, qk, sv, b, ro);
      }
    }
  }
  hipLaunchKernelGGL(k_final, dim3(8), dim3(256), 0, stream, sv, out);
}